// Round 4
// baseline (243.939 us; speedup 1.0000x reference)
//
#include <hip/hip_runtime.h>

#define B_ 4096
#define T_ 1024
#define H_ 15

// DPP helper. ctrl must be a compile-time constant.
// row_ror:n (ctrl 0x120+n): lane l reads lane (l-n)&15 within its 16-lane row.
// row_shr:n (ctrl 0x110+n): lane l reads lane l-n; shifted-in lanes get 0 (bound_ctrl).
template <int CTRL>
__device__ __forceinline__ float dpp_f(float v) {
  return __int_as_float(
      __builtin_amdgcn_update_dpp(0, __float_as_int(v), CTRL, 0xF, 0xF, true));
}

// ds_swizzle BitMode xor-16: new_lane = ((lane&0x1f)|0)^0x10 (within each 32-lane half).
__device__ __forceinline__ float swz_xor16(float v) {
  return __int_as_float(__builtin_amdgcn_ds_swizzle(__float_as_int(v), 0x401F));
}

// Split-K layout: 32 lanes per batch, 2 batches/wave, 2048 waves = 2 waves/SIMD.
// Round 3 falsified the register theory (VGPR 28->132, time flat, VALUBusy 48%):
// at 1 wave/SIMD the serial-recurrence latency is exposed. Two waves/SIMD hide
// each other's stalls; split-K halves the per-wave rotation count.
__global__ __attribute__((amdgpu_flat_work_group_size(256, 256),
                          amdgpu_waves_per_eu(2, 2)))
void rnn_tanh_kernel(
    const float* __restrict__ x, const float* __restrict__ w_ih,
    const float* __restrict__ w_hh, const float* __restrict__ b_ih,
    const float* __restrict__ b_hh, const float* __restrict__ w_lin,
    const float* __restrict__ b_lin, float* __restrict__ out) {
  const int tid = threadIdx.x;
  const int m = tid & 15;               // row within the 16-lane DPP row
  const int half = (tid >> 4) & 1;      // K-half: 0 = cols m-7..m, 1 = cols m+1..m+8
  const int b = blockIdx.x * 8 + (tid >> 5);  // batch (8 per 256-thread block)

  // Pre-scale by 2*log2(e): tanh(a) = 1 - 2/(exp2(S*a)+1), one v_exp_f32.
  const float S = 2.8853900817779268f;

  // half=1 lanes keep a rotated hidden copy g[m] = h[(m+8)&15]; at physical
  // rotation n they see g[(m-n)&15] = h[(m+8-n)&15], so their weights are
  // W[m][(m+8-n)&15] — together the halves cover all 16 columns of row m.
  float wr[8];
#pragma unroll
  for (int n = 0; n < 8; ++n) {
    const int c = (m + 8 * half - n) & 15;
    wr[n] = (m < H_ && c < H_) ? S * w_hh[m * H_ + c] : 0.0f;
  }
  // Row-m base term only in half 0 (added once; swizzle-combine shares it).
  const float wih  = (!half && m < H_) ? S * w_ih[m] : 0.0f;
  const float bias = (!half && m < H_) ? S * (b_ih[m] + b_hh[m]) : 0.0f;
  // This lane stores h[hrow]; head weight follows the stored permutation.
  const int hrow = (m + 8 * half) & 15;
  const float wlin = (hrow < H_) ? w_lin[hrow] : 0.0f;
  const float blin = b_lin[0];

  const float* xb = x + (size_t)b * T_;
  float* ob = out + (size_t)b * T_;

  float h = 0.0f;  // half0: h[m]; half1: h[(m+8)&15]. Pad rows stay exactly 0.

  auto step = [&](float xt) -> float {
    // Partial of row m over this lane's 8 columns (4 chains of depth 2).
    float c0 = fmaf(wr[0], h, fmaf(xt, wih, bias));
    float c1 = dpp_f<0x121>(h) * wr[1];
    float c2 = dpp_f<0x122>(h) * wr[2];
    float c3 = dpp_f<0x123>(h) * wr[3];
    c0 += dpp_f<0x124>(h) * wr[4];
    c1 += dpp_f<0x125>(h) * wr[5];
    c2 += dpp_f<0x126>(h) * wr[6];
    c3 += dpp_f<0x127>(h) * wr[7];
    const float part = (c0 + c1) + (c2 + c3);
    // Combine K-halves: lanes m and m+16 both get the full a[m] ...
    const float s = part + swz_xor16(part);
    // ... and half1 takes a[(m+8)&15] (row_ror:8; +8 == -8 mod 16) so it
    // stores the rotated copy g_next[m] = h_next[(m+8)&15].
    const float r = dpp_f<0x128>(s);
    const float a = half ? r : s;
    // tanh via pre-scaled exp2; saturates correctly at +/-inf.
    const float e = __builtin_amdgcn_exp2f(a);
    h = fmaf(-2.0f, __builtin_amdgcn_rcpf(e + 1.0f), 1.0f);
    // Output head: each 16-lane row holds all 16 h values (permuted), so a
    // row_shr butterfly gives the full dot in lane 15 of each row.
    float p = h * wlin;
    p = p + dpp_f<0x111>(p);
    p = p + dpp_f<0x112>(p);
    p = p + dpp_f<0x114>(p);
    p = p + dpp_f<0x118>(p);
    return p + blin;
  };

  // Depth-2 prefetch: next chunk ~8 steps ahead covers HBM latency.
  float4 x0 = *(const float4*)xb;
  float4 x1 = *(const float4*)(xb + 4);
  for (int t = 0; t < T_; t += 4) {
    const int tn = (t + 8 < T_) ? (t + 8) : 0;  // clamp: stay in-bounds
    const float4 x2 = *(const float4*)(xb + tn);
    const float o0 = step(x0.x);
    const float o1 = step(x0.y);
    const float o2 = step(x0.z);
    const float o3 = step(x0.w);
    if ((tid & 31) == 15) *(float4*)(ob + t) = make_float4(o0, o1, o2, o3);
    x0 = x1;
    x1 = x2;
  }
}

extern "C" void kernel_launch(void* const* d_in, const int* in_sizes, int n_in,
                              void* d_out, int out_size, void* d_ws, size_t ws_size,
                              hipStream_t stream) {
  (void)in_sizes; (void)n_in; (void)out_size; (void)d_ws; (void)ws_size;
  rnn_tanh_kernel<<<B_ / 8, 256, 0, stream>>>(
      (const float*)d_in[0], (const float*)d_in[1], (const float*)d_in[2],
      (const float*)d_in[3], (const float*)d_in[4], (const float*)d_in[5],
      (const float*)d_in[6], (float*)d_out);
}

// Round 5
// 219.977 us; speedup vs baseline: 1.1089x; 1.1089x over previous
//
#include <hip/hip_runtime.h>

#define B_ 4096
#define T_ 1024
#define H_ 15

// Fused DPP rotation ops via inline asm (GCNDPPCombine provably didn't fold
// mov_dpp+fma in R1-R3: VALUBusy implied ~80 instr/step). row_ror:n makes
// lane l read lane (l-n)&15 within its 16-lane row; DPP applies to src0.
// The compiler's hazard recognizer can't see DPP inside asm, so chain-head
// ops embed s_nop 2 (covers the 2-wait-state VALU-write -> DPP-read hazard,
// incl. the v_rcp trans write of u).
#define MUL_ROR(d, u, w, n)                                              \
  asm("s_nop 2\n\tv_mul_f32_dpp %0, %1, %2 row_ror:" #n                  \
      " row_mask:0xf bank_mask:0xf"                                      \
      : "=v"(d) : "v"(u), "v"(w))
#define FMAC_ROR(acc, u, w, n)                                           \
  asm("v_fmac_f32_dpp %0, %1, %2 row_ror:" #n                            \
      " row_mask:0xf bank_mask:0xf"                                      \
      : "+v"(acc) : "v"(u), "v"(w))
// Butterfly reduce-toward-lane-15. Default bound_ctrl (lanes with no source
// don't update) is equivalent to shifting in 0 for this reduction.
#define ADD_SHR(p, n)                                                    \
  do {                                                                   \
    float _t;                                                            \
    asm("s_nop 1\n\tv_add_f32_dpp %0, %1, %1 row_shr:" #n                \
        " row_mask:0xf bank_mask:0xf"                                    \
        : "=v"(_t) : "v"(p));                                            \
    p = _t;                                                              \
  } while (0)

// 16 lanes/batch, 4 batches/wave, 1024 waves = 1 wave/SIMD (R3 layout — best
// measured; R4 proved split-K's ds_swizzle adds ~120 cyc to the chain).
// u-recurrence: u_t = 1/(exp2(a_t)+1), h_t = 1 - 2*u_t (never materialized).
// a = S*(b_ih+b_hh+rowsum(W)) + S*w_ih*x - 2S * W u, S = 2*log2(e).
__global__ __attribute__((amdgpu_flat_work_group_size(256, 256),
                          amdgpu_waves_per_eu(1, 1)))
void rnn_tanh_kernel(
    const float* __restrict__ x, const float* __restrict__ w_ih,
    const float* __restrict__ w_hh, const float* __restrict__ b_ih,
    const float* __restrict__ b_hh, const float* __restrict__ w_lin,
    const float* __restrict__ b_lin, float* __restrict__ out) {
  const int tid = threadIdx.x;
  const int m = tid & 15;                  // hidden row this lane owns (15 = pad)
  const int b = blockIdx.x * 16 + (tid >> 4);  // batch index

  const float S = 2.8853900817779268f;     // 2*log2(e)

  // Rotation-permuted, -2S-scaled recurrent weights (rot n sees u[(m-n)&15]).
  float wr[16];
#pragma unroll
  for (int n = 0; n < 16; ++n) {
    const int c = (m - n) & 15;
    wr[n] = (m < H_ && c < H_) ? -2.0f * S * w_hh[m * H_ + c] : 0.0f;
  }
  float rowsum = 0.0f;
  if (m < H_)
    for (int j = 0; j < H_; ++j) rowsum += w_hh[m * H_ + j];
  const float wih2  = (m < H_) ? S * w_ih[m] : 0.0f;
  const float bias2 = (m < H_) ? S * (b_ih[m] + b_hh[m] + rowsum) : 0.0f;
  const float wl2   = (m < H_) ? -2.0f * w_lin[m] : 0.0f;
  float wsum = b_lin[0];
  for (int j = 0; j < H_; ++j) wsum += w_lin[j];
  const float C = wsum;                    // out = C - 2*sum(w_lin*u)

  const float* xb = x + (size_t)b * T_;
  float* ob = out + (size_t)b * T_;

  float u = 0.5f;  // h=0 -> u=0.5; pad lane: a=0 every step -> u stays 0.5

  auto step = [&](float xt) -> float {
    const float base = fmaf(xt, wih2, bias2);  // off the u critical path
    // rot 0 term (no DPP) — visible to compiler, hazards handled.
    float c4 = fmaf(wr[0], u, base);
    // 4 asm chains; each head is a MUL_ROR with embedded s_nop (hazard),
    // FMACs are ordered behind their head by the accumulator dependency.
    float cA, cB, cC, cD;
    MUL_ROR(cA, u, wr[1], 1);
    MUL_ROR(cB, u, wr[2], 2);
    MUL_ROR(cC, u, wr[3], 3);
    MUL_ROR(cD, u, wr[4], 4);
    FMAC_ROR(cA, u, wr[5], 5);
    FMAC_ROR(cB, u, wr[6], 6);
    FMAC_ROR(cC, u, wr[7], 7);
    FMAC_ROR(cD, u, wr[8], 8);
    FMAC_ROR(cA, u, wr[9], 9);
    FMAC_ROR(cB, u, wr[10], 10);
    FMAC_ROR(cC, u, wr[11], 11);
    FMAC_ROR(cD, u, wr[12], 12);
    FMAC_ROR(cA, u, wr[13], 13);
    FMAC_ROR(cB, u, wr[14], 14);
    FMAC_ROR(cC, u, wr[15], 15);
    const float a = (cA + cB) + ((cC + cD) + c4);
    // u = 1/(exp2(a)+1); saturates correctly (a->+inf: u->0 -> h->1;
    // a->-inf: u->1/1... exp2->0 -> u->1 -> h->-1).
    const float e = __builtin_amdgcn_exp2f(a);
    u = __builtin_amdgcn_rcpf(e + 1.0f);
    // Output head (issue-filler in the next step's trans shadow):
    // out = C - 2*sum_l w_lin[l]*u[l]; butterfly sum lands in lane 15.
    float p = u * wl2;
    ADD_SHR(p, 1);
    ADD_SHR(p, 2);
    ADD_SHR(p, 4);
    ADD_SHR(p, 8);
    return p + C;
  };

  // Depth-2 prefetch: next chunk ~8 steps ahead covers HBM latency.
  float4 x0 = *(const float4*)xb;
  float4 x1 = *(const float4*)(xb + 4);
  for (int t = 0; t < T_; t += 4) {
    const int tn = (t + 8 < T_) ? (t + 8) : 0;  // clamp: stay in-bounds
    const float4 x2 = *(const float4*)(xb + tn);
    const float o0 = step(x0.x);
    const float o1 = step(x0.y);
    const float o2 = step(x0.z);
    const float o3 = step(x0.w);
    if (m == 15) *(float4*)(ob + t) = make_float4(o0, o1, o2, o3);
    x0 = x1;
    x1 = x2;
  }
}

extern "C" void kernel_launch(void* const* d_in, const int* in_sizes, int n_in,
                              void* d_out, int out_size, void* d_ws, size_t ws_size,
                              hipStream_t stream) {
  (void)in_sizes; (void)n_in; (void)out_size; (void)d_ws; (void)ws_size;
  rnn_tanh_kernel<<<B_ / 16, 256, 0, stream>>>(
      (const float*)d_in[0], (const float*)d_in[1], (const float*)d_in[2],
      (const float*)d_in[3], (const float*)d_in[4], (const float*)d_in[5],
      (const float*)d_in[6], (float*)d_out);
}

// Round 6
// 186.849 us; speedup vs baseline: 1.3055x; 1.1773x over previous
//
#include <hip/hip_runtime.h>

#define B_ 4096
#define T_ 1024
#define H_ 15

// Fused DPP rotation ops via inline asm. row_ror:n: lane l reads lane
// (l-n)&15 within its 16-lane row; DPP applies to src0. The compiler's
// hazard recognizer can't see DPP inside asm, so chain heads embed s_nop 2
// (VALU/trans write -> DPP read needs 2 wait states).
#define MUL_ROR(d, u, w, n)                                              \
  asm("s_nop 2\n\tv_mul_f32_dpp %0, %1, %2 row_ror:" #n                  \
      " row_mask:0xf bank_mask:0xf"                                      \
      : "=v"(d) : "v"(u), "v"(w))
#define FMAC_ROR(acc, u, w, n)                                           \
  asm("v_fmac_f32_dpp %0, %1, %2 row_ror:" #n                            \
      " row_mask:0xf bank_mask:0xf"                                      \
      : "+v"(acc) : "v"(u), "v"(w))
// Butterfly reduce-toward-lane-15 (lane 15's dependency cone only reads
// valid source lanes, so default bound_ctrl semantics are safe).
#define ADD_SHR(p, n)                                                    \
  do {                                                                   \
    float _t;                                                            \
    asm("s_nop 1\n\tv_add_f32_dpp %0, %1, %1 row_shr:" #n                \
        " row_mask:0xf bank_mask:0xf"                                    \
        : "=v"(_t) : "v"(p));                                            \
    p = _t;                                                              \
  } while (0)

// Layout: 16 lanes/batch, 4 batches/wave, 1024 waves = 1 wave/SIMD.
// R1/R3/R5 invariance (~350 cyc/step regardless of compute) fingered the
// per-iteration x load's exposed HBM latency (~900 cyc, no reuse, prefetch
// regs rotated -> vmcnt(0) each iter). This version software-pipelines x
// with 8 buffers / 32-step unroll: refill-to-use distance = 29 steps.
__global__ __attribute__((amdgpu_flat_work_group_size(256, 256),
                          amdgpu_waves_per_eu(1, 1)))
void rnn_tanh_kernel(
    const float* __restrict__ x, const float* __restrict__ w_ih,
    const float* __restrict__ w_hh, const float* __restrict__ b_ih,
    const float* __restrict__ b_hh, const float* __restrict__ w_lin,
    const float* __restrict__ b_lin, float* __restrict__ out) {
  const int tid = threadIdx.x;
  const int m = tid & 15;                  // hidden row this lane owns (15 = pad)
  const int b = blockIdx.x * 16 + (tid >> 4);  // batch index

  const float S = 2.8853900817779268f;     // 2*log2(e)

  // u-recurrence: u = 1/(exp2(a)+1), h = 1-2u (never materialized).
  // a = S*(b_ih+b_hh+rowsum(W)) + S*w_ih*x - 2S*W u.
  float wr[16];
#pragma unroll
  for (int n = 0; n < 16; ++n) {
    const int c = (m - n) & 15;
    wr[n] = (m < H_ && c < H_) ? -2.0f * S * w_hh[m * H_ + c] : 0.0f;
  }
  float rowsum = 0.0f;
  if (m < H_)
    for (int j = 0; j < H_; ++j) rowsum += w_hh[m * H_ + j];
  const float wih2  = (m < H_) ? S * w_ih[m] : 0.0f;
  const float bias2 = (m < H_) ? S * (b_ih[m] + b_hh[m] + rowsum) : 0.0f;
  const float wl2   = (m < H_) ? -2.0f * w_lin[m] : 0.0f;
  float wsum = b_lin[0];
  for (int j = 0; j < H_; ++j) wsum += w_lin[j];
  const float C = wsum;                    // out = C - 2*sum(w_lin*u)

  const float* xb = x + (size_t)b * T_;
  float* ob = out + (size_t)b * T_;

  float u = 0.5f;  // h=0 -> u=0.5; pad lane: a=0 every step -> u stays 0.5

  auto step = [&](float xt) -> float {
    const float base = fmaf(xt, wih2, bias2);  // off the u critical path
    float c4 = fmaf(wr[0], u, base);
    float cA, cB, cC, cD;
    MUL_ROR(cA, u, wr[1], 1);
    MUL_ROR(cB, u, wr[2], 2);
    MUL_ROR(cC, u, wr[3], 3);
    MUL_ROR(cD, u, wr[4], 4);
    FMAC_ROR(cA, u, wr[5], 5);
    FMAC_ROR(cB, u, wr[6], 6);
    FMAC_ROR(cC, u, wr[7], 7);
    FMAC_ROR(cD, u, wr[8], 8);
    FMAC_ROR(cA, u, wr[9], 9);
    FMAC_ROR(cB, u, wr[10], 10);
    FMAC_ROR(cC, u, wr[11], 11);
    FMAC_ROR(cD, u, wr[12], 12);
    FMAC_ROR(cA, u, wr[13], 13);
    FMAC_ROR(cB, u, wr[14], 14);
    FMAC_ROR(cC, u, wr[15], 15);
    const float a = (cA + cB) + ((cC + cD) + c4);
    // u = 1/(exp2(a)+1); saturates correctly at +/-inf.
    const float e = __builtin_amdgcn_exp2f(a);
    u = __builtin_amdgcn_rcpf(e + 1.0f);
    // Output head; butterfly sum lands in lane 15.
    float p = u * wl2;
    ADD_SHR(p, 1);
    ADD_SHR(p, 2);
    ADD_SHR(p, 4);
    ADD_SHR(p, 8);
    return p + C;
  };

  // Software pipeline: 8 float4 x-buffers, 32 steps/iter. Each buffer is
  // refilled right after consumption for use 29 steps later (~2500 cyc at
  // the expected ~90 cyc/step) — far beyond the ~900-cyc HBM miss latency.
  // Up to 8 loads in flight; steady-state waitcnt is satisfied on arrival.
#define CHUNK(q, toff)                                               \
  do {                                                               \
    float4 _o;                                                       \
    _o.x = step(q.x);                                                \
    _o.y = step(q.y);                                                \
    _o.z = step(q.z);                                                \
    _o.w = step(q.w);                                                \
    if (m == 15) *(float4*)(ob + t + toff) = _o;                     \
    int _tn = t + 32 + toff;                                         \
    if (_tn >= T_) _tn = 0; /* clamped dummy refill near the end */  \
    q = *(const float4*)(xb + _tn);                                  \
  } while (0)

  float4 q0 = *(const float4*)(xb + 0);
  float4 q1 = *(const float4*)(xb + 4);
  float4 q2 = *(const float4*)(xb + 8);
  float4 q3 = *(const float4*)(xb + 12);
  float4 q4 = *(const float4*)(xb + 16);
  float4 q5 = *(const float4*)(xb + 20);
  float4 q6 = *(const float4*)(xb + 24);
  float4 q7 = *(const float4*)(xb + 28);

  for (int t = 0; t < T_; t += 32) {
    CHUNK(q0, 0);
    CHUNK(q1, 4);
    CHUNK(q2, 8);
    CHUNK(q3, 12);
    CHUNK(q4, 16);
    CHUNK(q5, 20);
    CHUNK(q6, 24);
    CHUNK(q7, 28);
  }
#undef CHUNK
}

extern "C" void kernel_launch(void* const* d_in, const int* in_sizes, int n_in,
                              void* d_out, int out_size, void* d_ws, size_t ws_size,
                              hipStream_t stream) {
  (void)in_sizes; (void)n_in; (void)out_size; (void)d_ws; (void)ws_size;
  rnn_tanh_kernel<<<B_ / 16, 256, 0, stream>>>(
      (const float*)d_in[0], (const float*)d_in[1], (const float*)d_in[2],
      (const float*)d_in[3], (const float*)d_in[4], (const float*)d_in[5],
      (const float*)d_in[6], (float*)d_out);
}

// Round 7
// 154.433 us; speedup vs baseline: 1.5796x; 1.2099x over previous
//
#include <hip/hip_runtime.h>

#define B_ 4096
#define T_ 1024
#define H_ 15

// ===== Whole RNN step as ONE hand-scheduled asm block =====
// Registers: u (in/out) = 1/(exp2(a)+1) state; pp (in/out) = pending
// per-lane head product of the PREVIOUS step; o_ (out) = finished output
// of the PREVIOUS step (valid in lane 15).
//
// Schedule rationale:
//  - 4 MAC chains (A: rot 1,5,9,13 | B: 2,6,10,14 | C: 3,7,11,15 |
//    D: rot0+base,4,8,12) issue interleaved with the previous step's
//    4-level head butterfly, giving every v_add_f32_dpp >=2 real
//    instructions of spacing after its pp write (DPP read-after-VALU-write
//    needs 2 wait states) -> no s_nops in the butterfly.
//  - s_nop 1 at block head covers (prev) v_rcp write -> DPP read of u.
//  - s_nop 0 after each trans op covers trans->VALU consumer (1 wait).
//  - All DPP reads of u/wr are >=3 slots from their writers.  Butterfly
//    validity: lane 15's reduction cone only reads lanes 0..14 (row_shr),
//    so shifted-in lanes never contaminate the stored result.
#define STEP(XT, ODST)                                                        \
  do {                                                                        \
    float base_ = fmaf((XT), wih2, bias2);                                    \
    float cA_, cB_, cC_, cD_, e_;                                             \
    asm("s_nop 1\n\t"                                                         \
        "v_mul_f32_dpp %[cA], %[u], %[w1] row_ror:1 row_mask:0xf bank_mask:0xf\n\t"  \
        "v_mul_f32_dpp %[cB], %[u], %[w2] row_ror:2 row_mask:0xf bank_mask:0xf\n\t"  \
        "v_mul_f32_dpp %[cC], %[u], %[w3] row_ror:3 row_mask:0xf bank_mask:0xf\n\t"  \
        "v_fma_f32 %[cD], %[u], %[w0], %[bs]\n\t"                             \
        "v_add_f32_dpp %[pp], %[pp], %[pp] row_shr:1 row_mask:0xf bank_mask:0xf\n\t" \
        "v_fmac_f32_dpp %[cA], %[u], %[w5] row_ror:5 row_mask:0xf bank_mask:0xf\n\t" \
        "v_fmac_f32_dpp %[cB], %[u], %[w6] row_ror:6 row_mask:0xf bank_mask:0xf\n\t" \
        "v_add_f32_dpp %[pp], %[pp], %[pp] row_shr:2 row_mask:0xf bank_mask:0xf\n\t" \
        "v_fmac_f32_dpp %[cC], %[u], %[w7] row_ror:7 row_mask:0xf bank_mask:0xf\n\t" \
        "v_fmac_f32_dpp %[cD], %[u], %[w4] row_ror:4 row_mask:0xf bank_mask:0xf\n\t" \
        "v_add_f32_dpp %[pp], %[pp], %[pp] row_shr:4 row_mask:0xf bank_mask:0xf\n\t" \
        "v_fmac_f32_dpp %[cA], %[u], %[w9] row_ror:9 row_mask:0xf bank_mask:0xf\n\t" \
        "v_fmac_f32_dpp %[cB], %[u], %[w10] row_ror:10 row_mask:0xf bank_mask:0xf\n\t" \
        "v_add_f32_dpp %[pp], %[pp], %[pp] row_shr:8 row_mask:0xf bank_mask:0xf\n\t" \
        "v_fmac_f32_dpp %[cC], %[u], %[w11] row_ror:11 row_mask:0xf bank_mask:0xf\n\t" \
        "v_fmac_f32_dpp %[cD], %[u], %[w8] row_ror:8 row_mask:0xf bank_mask:0xf\n\t"  \
        "v_add_f32 %[o], %[pp], %[Cc]\n\t"                                    \
        "v_fmac_f32_dpp %[cA], %[u], %[w13] row_ror:13 row_mask:0xf bank_mask:0xf\n\t" \
        "v_fmac_f32_dpp %[cB], %[u], %[w14] row_ror:14 row_mask:0xf bank_mask:0xf\n\t" \
        "v_fmac_f32_dpp %[cC], %[u], %[w15] row_ror:15 row_mask:0xf bank_mask:0xf\n\t" \
        "v_fmac_f32_dpp %[cD], %[u], %[w12] row_ror:12 row_mask:0xf bank_mask:0xf\n\t" \
        "v_add_f32 %[cA], %[cA], %[cB]\n\t"                                   \
        "v_add_f32 %[cC], %[cC], %[cD]\n\t"                                   \
        "v_add_f32 %[cA], %[cA], %[cC]\n\t"                                   \
        "v_exp_f32 %[e], %[cA]\n\t"                                           \
        "s_nop 0\n\t"                                                         \
        "v_add_f32 %[e], 1.0, %[e]\n\t"                                       \
        "v_rcp_f32 %[u], %[e]\n\t"                                            \
        "s_nop 0\n\t"                                                         \
        "v_mul_f32 %[pp], %[u], %[wl]\n\t"                                    \
        : [u] "+v"(u), [pp] "+v"(pp), [o] "=&v"(ODST), [cA] "=&v"(cA_),       \
          [cB] "=&v"(cB_), [cC] "=&v"(cC_), [cD] "=&v"(cD_), [e] "=&v"(e_)    \
        : [bs] "v"(base_), [wl] "v"(wl2), [Cc] "v"(C),                        \
          [w0] "v"(wr[0]), [w1] "v"(wr[1]), [w2] "v"(wr[2]),                  \
          [w3] "v"(wr[3]), [w4] "v"(wr[4]), [w5] "v"(wr[5]),                  \
          [w6] "v"(wr[6]), [w7] "v"(wr[7]), [w8] "v"(wr[8]),                  \
          [w9] "v"(wr[9]), [w10] "v"(wr[10]), [w11] "v"(wr[11]),              \
          [w12] "v"(wr[12]), [w13] "v"(wr[13]), [w14] "v"(wr[14]),            \
          [w15] "v"(wr[15]));                                                 \
  } while (0)

// Epilogue-only butterfly (runs once; s_nops are fine here).
#define ADD_SHR_EPI(p, n)                                                     \
  do {                                                                        \
    float _t;                                                                 \
    asm("s_nop 1\n\tv_add_f32_dpp %0, %1, %1 row_shr:" #n                     \
        " row_mask:0xf bank_mask:0xf"                                         \
        : "=v"(_t) : "v"(p));                                                 \
    p = _t;                                                                   \
  } while (0)

// Pipeline position K (0..31) of a 32-step block: runs step t+K, retires the
// output of step t+K-1, stores each finished 4-pack, refills one x buffer.
#define POS(K, XV)                                                            \
  do {                                                                        \
    float o_;                                                                 \
    STEP(XV, o_);                                                             \
    osta[((K) + 3) & 3] = o_;                                                 \
    if (((K) & 3) == 0) {                                                     \
      if ((K) > 0 || t > 0) {                                                 \
        if (m == 15)                                                          \
          *(float4*)(ob + t + (K) - 4) =                                      \
              make_float4(osta[0], osta[1], osta[2], osta[3]);                \
      }                                                                       \
    }                                                                         \
    if (((K) & 3) == 3) {                                                     \
      int _tn = t + 32 + (((K) >> 2) << 2);                                   \
      if (_tn >= T_) _tn = 0; /* clamped dummy refill near the end */         \
      qq[(K) >> 2] = *(const float4*)(xb + _tn);                              \
    }                                                                         \
  } while (0)

// 16 lanes/batch, 4 batches/wave, 1024 waves = 1 wave/SIMD.
// u-recurrence: u = 1/(exp2(a)+1), h = 1-2u (never materialized).
__global__ __attribute__((amdgpu_flat_work_group_size(256, 256),
                          amdgpu_waves_per_eu(1, 1)))
void rnn_tanh_kernel(
    const float* __restrict__ x, const float* __restrict__ w_ih,
    const float* __restrict__ w_hh, const float* __restrict__ b_ih,
    const float* __restrict__ b_hh, const float* __restrict__ w_lin,
    const float* __restrict__ b_lin, float* __restrict__ out) {
  const int tid = threadIdx.x;
  const int m = tid & 15;                      // hidden row (15 = pad)
  const int b = blockIdx.x * 16 + (tid >> 4);  // batch index

  const float S = 2.8853900817779268f;         // 2*log2(e)

  // Rotation-permuted, -2S-scaled recurrent weights (rot n sees u[(m-n)&15]).
  float wr[16];
#pragma unroll
  for (int n = 0; n < 16; ++n) {
    const int c = (m - n) & 15;
    wr[n] = (m < H_ && c < H_) ? -2.0f * S * w_hh[m * H_ + c] : 0.0f;
  }
  float rowsum = 0.0f;
  if (m < H_)
    for (int j = 0; j < H_; ++j) rowsum += w_hh[m * H_ + j];
  const float wih2  = (m < H_) ? S * w_ih[m] : 0.0f;
  const float bias2 = (m < H_) ? S * (b_ih[m] + b_hh[m] + rowsum) : 0.0f;
  const float wl2   = (m < H_) ? -2.0f * w_lin[m] : 0.0f;
  float wsum = b_lin[0];
  for (int j = 0; j < H_; ++j) wsum += w_lin[j];
  const float C = wsum;                        // out = C - 2*sum(w_lin*u)

  const float* xb = x + (size_t)b * T_;
  float* ob = out + (size_t)b * T_;

  float u = 0.5f;        // h=0 -> u=0.5; pad lane stays 0.5 (a=0 every step)
  float pp = u * wl2;    // pending head product ("step -1" — retired value discarded)
  float osta[4];         // output staging (constant-indexed -> registers)

  // 8-buffer x pipeline (R6): refill-to-use distance = 29 steps.
  float4 qq[8];
#pragma unroll
  for (int j = 0; j < 8; ++j) qq[j] = *(const float4*)(xb + 4 * j);

  for (int t = 0; t < T_; t += 32) {
    POS(0,  qq[0].x); POS(1,  qq[0].y); POS(2,  qq[0].z); POS(3,  qq[0].w);
    POS(4,  qq[1].x); POS(5,  qq[1].y); POS(6,  qq[1].z); POS(7,  qq[1].w);
    POS(8,  qq[2].x); POS(9,  qq[2].y); POS(10, qq[2].z); POS(11, qq[2].w);
    POS(12, qq[3].x); POS(13, qq[3].y); POS(14, qq[3].z); POS(15, qq[3].w);
    POS(16, qq[4].x); POS(17, qq[4].y); POS(18, qq[4].z); POS(19, qq[4].w);
    POS(20, qq[5].x); POS(21, qq[5].y); POS(22, qq[5].z); POS(23, qq[5].w);
    POS(24, qq[6].x); POS(25, qq[6].y); POS(26, qq[6].z); POS(27, qq[6].w);
    POS(28, qq[7].x); POS(29, qq[7].y); POS(30, qq[7].z); POS(31, qq[7].w);
  }

  // Epilogue: retire step T_-1's head and store the final 4-pack.
  ADD_SHR_EPI(pp, 1);
  ADD_SHR_EPI(pp, 2);
  ADD_SHR_EPI(pp, 4);
  ADD_SHR_EPI(pp, 8);
  osta[3] = pp + C;
  if (m == 15)
    *(float4*)(ob + T_ - 4) = make_float4(osta[0], osta[1], osta[2], osta[3]);
}

extern "C" void kernel_launch(void* const* d_in, const int* in_sizes, int n_in,
                              void* d_out, int out_size, void* d_ws, size_t ws_size,
                              hipStream_t stream) {
  (void)in_sizes; (void)n_in; (void)out_size; (void)d_ws; (void)ws_size;
  rnn_tanh_kernel<<<B_ / 16, 256, 0, stream>>>(
      (const float*)d_in[0], (const float*)d_in[1], (const float*)d_in[2],
      (const float*)d_in[3], (const float*)d_in[4], (const float*)d_in[5],
      (const float*)d_in[6], (float*)d_out);
}

// Round 9
// 141.685 us; speedup vs baseline: 1.7217x; 1.0900x over previous
//
#include <hip/hip_runtime.h>

#define B_ 4096
#define T_ 1024
#define H_ 15

// ===== Whole RNN step as ONE hand-scheduled asm block =====
// State: u = 1/(exp2(a)+1)  (h = 1-2u, never materialized).
// Head-fold: lane 15 (pad row) carries the output head in its MAC chains —
// wr15[n] = -2*w_lin[(15-n)&15], bias15 = C — so the tree sum on lane 15 is
// C - 2*sum(w_lin*u_prev) = out[t-1]  (chains read the u that ENTERS the
// block, i.e. u_{t-1}: one-step-delayed output, retired like R7's pp).
// u[15] itself is garbage but never consumed: every lane's column-15 weight
// is 0 and lane 15's own chains only read u[0..14].
//
// Hazard bookkeeping (DPP read needs 2 wait states after the src write):
//  - tail "s_nop 0" + next block's head v_fma = 2 states between v_rcp(u)
//    and the first v_mul_f32_dpp(u).
//  - same-chain fmac spacing >= 3 instructions.
//  - trans->consumer (exp->add) covered by s_nop 0.
#define STEP(XT, ODST)                                                        \
  do {                                                                        \
    float bs_, cB_, cC_, cD_, e_;                                             \
    asm("v_fma_f32 %[bs], %[xt], %[wih], %[bias]\n\t"                         \
        "v_mul_f32_dpp %[acc], %[u], %[w1] row_ror:1 row_mask:0xf bank_mask:0xf\n\t"  \
        "v_mul_f32_dpp %[cB], %[u], %[w2] row_ror:2 row_mask:0xf bank_mask:0xf\n\t"   \
        "v_mul_f32_dpp %[cC], %[u], %[w3] row_ror:3 row_mask:0xf bank_mask:0xf\n\t"   \
        "v_fma_f32 %[cD], %[u], %[w0], %[bs]\n\t"                             \
        "v_fmac_f32_dpp %[acc], %[u], %[w5] row_ror:5 row_mask:0xf bank_mask:0xf\n\t" \
        "v_fmac_f32_dpp %[cB], %[u], %[w6] row_ror:6 row_mask:0xf bank_mask:0xf\n\t"  \
        "v_fmac_f32_dpp %[cC], %[u], %[w7] row_ror:7 row_mask:0xf bank_mask:0xf\n\t"  \
        "v_fmac_f32_dpp %[cD], %[u], %[w4] row_ror:4 row_mask:0xf bank_mask:0xf\n\t"  \
        "v_fmac_f32_dpp %[acc], %[u], %[w9] row_ror:9 row_mask:0xf bank_mask:0xf\n\t" \
        "v_fmac_f32_dpp %[cB], %[u], %[w10] row_ror:10 row_mask:0xf bank_mask:0xf\n\t" \
        "v_fmac_f32_dpp %[cC], %[u], %[w11] row_ror:11 row_mask:0xf bank_mask:0xf\n\t" \
        "v_fmac_f32_dpp %[cD], %[u], %[w8] row_ror:8 row_mask:0xf bank_mask:0xf\n\t"  \
        "v_fmac_f32_dpp %[acc], %[u], %[w13] row_ror:13 row_mask:0xf bank_mask:0xf\n\t" \
        "v_fmac_f32_dpp %[cB], %[u], %[w14] row_ror:14 row_mask:0xf bank_mask:0xf\n\t" \
        "v_fmac_f32_dpp %[cC], %[u], %[w15] row_ror:15 row_mask:0xf bank_mask:0xf\n\t" \
        "v_fmac_f32_dpp %[cD], %[u], %[w12] row_ror:12 row_mask:0xf bank_mask:0xf\n\t" \
        "v_add_f32 %[acc], %[acc], %[cB]\n\t"                                 \
        "v_add_f32 %[cC], %[cC], %[cD]\n\t"                                   \
        "v_add_f32 %[acc], %[acc], %[cC]\n\t"                                 \
        "v_exp_f32 %[e], %[acc]\n\t"                                          \
        "s_nop 0\n\t"                                                         \
        "v_add_f32 %[e], 1.0, %[e]\n\t"                                       \
        "v_rcp_f32 %[u], %[e]\n\t"                                            \
        "s_nop 0\n\t"                                                         \
        : [u] "+v"(u), [acc] "=&v"(ODST), [bs] "=&v"(bs_), [cB] "=&v"(cB_),   \
          [cC] "=&v"(cC_), [cD] "=&v"(cD_), [e] "=&v"(e_)                     \
        : [xt] "v"(XT), [wih] "v"(wih2), [bias] "v"(bias2),                   \
          [w0] "v"(wr[0]), [w1] "v"(wr[1]), [w2] "v"(wr[2]),                  \
          [w3] "v"(wr[3]), [w4] "v"(wr[4]), [w5] "v"(wr[5]),                  \
          [w6] "v"(wr[6]), [w7] "v"(wr[7]), [w8] "v"(wr[8]),                  \
          [w9] "v"(wr[9]), [w10] "v"(wr[10]), [w11] "v"(wr[11]),              \
          [w12] "v"(wr[12]), [w13] "v"(wr[13]), [w14] "v"(wr[14]),            \
          [w15] "v"(wr[15]));                                                 \
  } while (0)

// Pipeline position K (0..31): runs step t+K; lane 15's tree value is
// out[t+K-1] -> staged at index (K-1)&3; a finished 4-pack (steps
// t+K-4..t+K-1) is stored at K%4==0 (skipping the very first, garbage,
// retirement); one x buffer refilled per 4 steps (refill-to-use = 29 steps).
#define POS(K, XV)                                                            \
  do {                                                                        \
    float o_;                                                                 \
    STEP(XV, o_);                                                             \
    osta[((K) + 3) & 3] = o_;                                                 \
    if (((K) & 3) == 0) {                                                     \
      if ((K) > 0 || t > 0) {                                                 \
        if (m == 15)                                                          \
          *(float4*)(ob + t + (K) - 4) =                                      \
              make_float4(osta[0], osta[1], osta[2], osta[3]);                \
      }                                                                       \
    }                                                                         \
    if (((K) & 3) == 3) {                                                     \
      int _tn = t + 32 + (((K) >> 2) << 2);                                   \
      if (_tn >= T_) _tn = 0; /* clamped dummy refill near the end */         \
      qq[(K) >> 2] = *(const float4*)(xb + _tn);                              \
    }                                                                         \
  } while (0)

// 16 lanes/batch, 4 batches/wave, 1024 waves = 1 wave/SIMD.
__global__ __attribute__((amdgpu_flat_work_group_size(256, 256),
                          amdgpu_waves_per_eu(1, 1)))
void rnn_tanh_kernel(
    const float* __restrict__ x, const float* __restrict__ w_ih,
    const float* __restrict__ w_hh, const float* __restrict__ b_ih,
    const float* __restrict__ b_hh, const float* __restrict__ w_lin,
    const float* __restrict__ b_lin, float* __restrict__ out) {
  const int tid = threadIdx.x;
  const int m = tid & 15;                      // hidden row (15 = head lane)
  const int b = blockIdx.x * 16 + (tid >> 4);  // batch index

  const float S = 2.8853900817779268f;         // 2*log2(e)

  // out = C - 2*sum(w_lin*u), C = b_lin + sum(w_lin).
  float wsum = b_lin[0];
  for (int j = 0; j < H_; ++j) wsum += w_lin[j];
  const float C = wsum;

  // Rotation-permuted weights (rot n reads u[(m-n)&15]).
  // Lanes 0..14: recurrence rows, scaled by -2S. Lane 15: head weights.
  float wr[16];
#pragma unroll
  for (int n = 0; n < 16; ++n) {
    const int c = (m - n) & 15;
    if (m < H_)
      wr[n] = (c < H_) ? -2.0f * S * w_hh[m * H_ + c] : 0.0f;
    else
      wr[n] = (c < H_) ? -2.0f * w_lin[c] : 0.0f;
  }
  float rowsum = 0.0f;
  if (m < H_)
    for (int j = 0; j < H_; ++j) rowsum += w_hh[m * H_ + j];
  const float wih2  = (m < H_) ? S * w_ih[m] : 0.0f;
  const float bias2 = (m < H_) ? S * (b_ih[m] + b_hh[m] + rowsum) : C;

  const float* xb = x + (size_t)b * T_;
  float* ob = out + (size_t)b * T_;

  float u = 0.5f;  // h=0 -> u=0.5 (lane 15's u is never consumed)
  asm("s_nop 1" : "+v"(u));  // guard: >=2 wait states before first DPP read
  float osta[4];             // output staging (constant-indexed -> registers)

  // 8-buffer x software pipeline (R6).
  float4 qq[8];
#pragma unroll
  for (int j = 0; j < 8; ++j) qq[j] = *(const float4*)(xb + 4 * j);

  for (int t = 0; t < T_; t += 32) {
    POS(0,  qq[0].x); POS(1,  qq[0].y); POS(2,  qq[0].z); POS(3,  qq[0].w);
    POS(4,  qq[1].x); POS(5,  qq[1].y); POS(6,  qq[1].z); POS(7,  qq[1].w);
    POS(8,  qq[2].x); POS(9,  qq[2].y); POS(10, qq[2].z); POS(11, qq[2].w);
    POS(12, qq[3].x); POS(13, qq[3].y); POS(14, qq[3].z); POS(15, qq[3].w);
    POS(16, qq[4].x); POS(17, qq[4].y); POS(18, qq[4].z); POS(19, qq[4].w);
    POS(20, qq[5].x); POS(21, qq[5].y); POS(22, qq[5].z); POS(23, qq[5].w);
    POS(24, qq[6].x); POS(25, qq[6].y); POS(26, qq[6].z); POS(27, qq[6].w);
    POS(28, qq[7].x); POS(29, qq[7].y); POS(30, qq[7].z); POS(31, qq[7].w);
  }

  // Epilogue: one extra STEP (dummy x) — its lane-15 tree reads the final
  // u_{T-1}, producing out[T-1]; complete and store the last 4-pack.
  {
    float o_;
    STEP(0.0f, o_);
    osta[3] = o_;
    if (m == 15)
      *(float4*)(ob + T_ - 4) = make_float4(osta[0], osta[1], osta[2], osta[3]);
  }
}

extern "C" void kernel_launch(void* const* d_in, const int* in_sizes, int n_in,
                              void* d_out, int out_size, void* d_ws, size_t ws_size,
                              hipStream_t stream) {
  (void)in_sizes; (void)n_in; (void)out_size; (void)d_ws; (void)ws_size;
  rnn_tanh_kernel<<<B_ / 16, 256, 0, stream>>>(
      (const float*)d_in[0], (const float*)d_in[1], (const float*)d_in[2],
      (const float*)d_in[3], (const float*)d_in[4], (const float*)d_in[5],
      (const float*)d_in[6], (float*)d_out);
}